// Round 1
// baseline (338.710 us; speedup 1.0000x reference)
//
#include <hip/hip_runtime.h>
#include <hip/hip_bf16.h>

#define NN 10000
#define TT 8
#define CC 16
#define OO 64
#define KK 16
#define LL 3
#define NCHUNK 157   // ceil(10000/64)

typedef __bf16 bf16;
typedef __attribute__((ext_vector_type(8))) __bf16 bf16x8;
typedef __attribute__((ext_vector_type(4))) float f32x4;

__device__ __forceinline__ float sigf(float x) { return 1.0f / (1.0f + __expf(-x)); }
__device__ __forceinline__ float tanhf_(float x) { return 2.0f / (1.0f + __expf(-2.0f * x)) - 1.0f; }

// ---------------------------------------------------------------------------
// prep: repack LSTM weights into bf16 B-fragment order + combine biases.
// wts layout (bf16): [l][mat][kh][nt][n16][k32], offset = ((((l*2+mat)*2+kh)*16+nt)*16+n)*32+k
// ---------------------------------------------------------------------------
__global__ void prep_kernel(const float* __restrict__ W_ih, const float* __restrict__ W_hh,
                            const float* __restrict__ b_ih, const float* __restrict__ b_hh,
                            bf16* __restrict__ wts, float* __restrict__ bias) {
    int id = blockIdx.x * 256 + threadIdx.x;
    if (id < LL * 2 * 256 * 64) {
        int col = id & 63;
        int row = (id >> 6) & 255;
        int mat = (id >> 14) & 1;
        int l = id >> 15;
        const float* src = mat ? W_hh : W_ih;
        float w = src[(l * 256 + row) * 64 + col];
        int kh = col >> 5, nt = row >> 4, nn = row & 15, kk = col & 31;
        wts[((((l * 2 + mat) * 2 + kh) * 16 + nt) * 16 + nn) * 32 + kk] = (bf16)w;
    } else {
        int id2 = id - LL * 2 * 256 * 64;
        if (id2 < LL * 256) bias[id2] = b_ih[id2] + b_hh[id2];
    }
}

// ---------------------------------------------------------------------------
// conv: per (l,t,node): gather K=16 neighbor rows, rel = g - x, MFMA with
// conv_w^T (Kdim=C=16 zero-padded to 32), max over neighbors, +bias, bf16 out.
// grid = L*T*NCHUNK blocks; block = 256 (4 waves); each wave: 16 nodes.
// ---------------------------------------------------------------------------
__global__ __launch_bounds__(256) void conv_kernel(
    const float* __restrict__ X, const int* __restrict__ As,
    const float* __restrict__ conv_w, const float* __restrict__ conv_b,
    bf16* __restrict__ feat) {
    const int lane = threadIdx.x & 63;
    const int wv = threadIdx.x >> 6;
    const int c16 = lane & 15;  // A-row (neighbor) / B-col (output) index
    const int q = lane >> 4;    // quad

    const int chunk = blockIdx.x % NCHUNK;
    const int lt = blockIdx.x / NCHUNK;
    const int l = lt >> 3, t = lt & 7;

    // B-fragments: B[k=c][n=o'] = conv_w[l][nt*16+o'][c]; quads 2,3 are zero pad.
    bf16x8 bw[4];
#pragma unroll
    for (int nt = 0; nt < 4; ++nt) {
        bf16x8 b;
#pragma unroll
        for (int j = 0; j < 8; ++j) b[j] = (bf16)0.0f;
        if (q < 2) {
            const float* wp = conv_w + ((l * 64 + nt * 16 + c16) * 16 + q * 8);
#pragma unroll
            for (int j = 0; j < 8; ++j) b[j] = (bf16)wp[j];
        }
        bw[nt] = b;
    }
    const float bias_v = conv_b[l * 64 + q * 16 + c16];

    for (int i = 0; i < 16; ++i) {
        const int n = chunk * 64 + wv * 16 + i;
        if (n >= NN) break;  // wave-uniform
        const int a = As[((l * 8 + t) * NN + n) * 16 + c16];

        bf16x8 af;
#pragma unroll
        for (int j = 0; j < 8; ++j) af[j] = (bf16)0.0f;
        if (q < 2) {
            const float* gp = X + (a * 8 + t) * 16 + q * 8;
            const float* sp = X + (n * 8 + t) * 16 + q * 8;
            float g[8], s[8];
            *(f32x4*)&g[0] = *(const f32x4*)gp;
            *(f32x4*)&g[4] = *(const f32x4*)(gp + 4);
            *(f32x4*)&s[0] = *(const f32x4*)sp;
            *(f32x4*)&s[4] = *(const f32x4*)(sp + 4);
#pragma unroll
            for (int j = 0; j < 8; ++j) af[j] = (bf16)(g[j] - s[j]);
        }

        f32x4 a0 = {0.f, 0.f, 0.f, 0.f}, a1 = a0, a2 = a0, a3 = a0;
        a0 = __builtin_amdgcn_mfma_f32_16x16x32_bf16(af, bw[0], a0, 0, 0, 0);
        a1 = __builtin_amdgcn_mfma_f32_16x16x32_bf16(af, bw[1], a1, 0, 0, 0);
        a2 = __builtin_amdgcn_mfma_f32_16x16x32_bf16(af, bw[2], a2, 0, 0, 0);
        a3 = __builtin_amdgcn_mfma_f32_16x16x32_bf16(af, bw[3], a3, 0, 0, 0);

        // max over neighbors (M-rows): 4 regs then butterfly across quads.
        float m0 = fmaxf(fmaxf(a0[0], a0[1]), fmaxf(a0[2], a0[3]));
        float m1 = fmaxf(fmaxf(a1[0], a1[1]), fmaxf(a1[2], a1[3]));
        float m2 = fmaxf(fmaxf(a2[0], a2[1]), fmaxf(a2[2], a2[3]));
        float m3 = fmaxf(fmaxf(a3[0], a3[1]), fmaxf(a3[2], a3[3]));
        m0 = fmaxf(m0, __shfl_xor(m0, 16)); m0 = fmaxf(m0, __shfl_xor(m0, 32));
        m1 = fmaxf(m1, __shfl_xor(m1, 16)); m1 = fmaxf(m1, __shfl_xor(m1, 32));
        m2 = fmaxf(m2, __shfl_xor(m2, 16)); m2 = fmaxf(m2, __shfl_xor(m2, 32));
        m3 = fmaxf(m3, __shfl_xor(m3, 16)); m3 = fmaxf(m3, __shfl_xor(m3, 32));
        float v = (q & 2) ? ((q & 1) ? m3 : m2) : ((q & 1) ? m1 : m0);
        feat[((l * 8 + t) * NN + n) * 64 + q * 16 + c16] = (bf16)(v + bias_v);
    }
}

// ---------------------------------------------------------------------------
// lstm: 157 blocks x 4 waves; wave owns 16 nodes; loops levels 0..2 so the
// max-over-L is an in-block RMW on d_out (no races). Weights in LDS (64 KB),
// h LDS round-trip per step (C/D -> A transpose), c in C/D-layout registers.
// ---------------------------------------------------------------------------
__global__ __launch_bounds__(256) void lstm_kernel(
    const bf16* __restrict__ feat, const bf16* __restrict__ wts,
    const float* __restrict__ bias, float* __restrict__ out) {
    __shared__ __align__(16) bf16 ldsw[2 * 2 * 16 * 16 * 32];  // 64 KB
    __shared__ __align__(16) bf16 hlds[4 * 16 * 72];           // 9 KB (72-pad rows)

    const int tid = threadIdx.x;
    const int lane = tid & 63;
    const int wv = tid >> 6;
    const int c16 = lane & 15;
    const int q = lane >> 4;
    const int node0 = blockIdx.x * 64 + wv * 16;

    int nA = node0 + c16;            // node for A-fragment row (lane&15)
    if (nA > NN - 1) nA = NN - 1;    // clamp loads; stores are masked

    for (int l = 0; l < LL; ++l) {
        __syncthreads();  // everyone done with previous level's ldsw
        {   // stage this level's weights: 4096 x 16B
            const bf16x8* src = (const bf16x8*)(wts + l * 32768);
            bf16x8* dst = (bf16x8*)ldsw;
#pragma unroll
            for (int i = 0; i < 16; ++i) dst[tid + i * 256] = src[tid + i * 256];
        }
        {   // zero this wave's h region
            bf16* hz = hlds + wv * 1152;
            for (int i = lane; i < 1152; i += 64) hz[i] = (bf16)0.0f;
        }
        float brg[16];
#pragma unroll
        for (int nt = 0; nt < 16; ++nt) brg[nt] = bias[l * 256 + nt * 16 + c16];
        __syncthreads();

        float c_r[4][4];
#pragma unroll
        for (int a = 0; a < 4; ++a)
#pragma unroll
            for (int b = 0; b < 4; ++b) c_r[a][b] = 0.0f;

        for (int t = 0; t < TT; ++t) {
            // A-fragments: x from global feat, h from LDS
            const bf16* fb = feat + (((l * 8 + t) * NN + nA) * 64 + q * 8);
            bf16x8 ax0 = *(const bf16x8*)(fb);
            bf16x8 ax1 = *(const bf16x8*)(fb + 32);
            const bf16* hb = hlds + wv * 1152 + c16 * 72 + q * 8;
            bf16x8 ah0 = *(const bf16x8*)(hb);
            bf16x8 ah1 = *(const bf16x8*)(hb + 32);

            f32x4 acc[16];
#pragma unroll
            for (int nt = 0; nt < 16; ++nt) {
                float b = brg[nt];
                acc[nt] = (f32x4){b, b, b, b};
            }
            const int wb = c16 * 32 + q * 8;
#pragma unroll
            for (int nt = 0; nt < 16; ++nt) {
                bf16x8 bi0 = *(const bf16x8*)(ldsw + nt * 512 + wb);
                acc[nt] = __builtin_amdgcn_mfma_f32_16x16x32_bf16(ax0, bi0, acc[nt], 0, 0, 0);
                bf16x8 bi1 = *(const bf16x8*)(ldsw + 8192 + nt * 512 + wb);
                acc[nt] = __builtin_amdgcn_mfma_f32_16x16x32_bf16(ax1, bi1, acc[nt], 0, 0, 0);
                bf16x8 bh0 = *(const bf16x8*)(ldsw + 16384 + nt * 512 + wb);
                acc[nt] = __builtin_amdgcn_mfma_f32_16x16x32_bf16(ah0, bh0, acc[nt], 0, 0, 0);
                bf16x8 bh1 = *(const bf16x8*)(ldsw + 16384 + 8192 + nt * 512 + wb);
                acc[nt] = __builtin_amdgcn_mfma_f32_16x16x32_bf16(ah1, bh1, acc[nt], 0, 0, 0);
            }
            // elementwise LSTM cell; C/D layout: col=lane&15, row=q*4+r
#pragma unroll
            for (int ot = 0; ot < 4; ++ot) {
#pragma unroll
                for (int r = 0; r < 4; ++r) {
                    float iv = acc[ot][r];
                    float fv = acc[ot + 4][r];
                    float gv = acc[ot + 8][r];
                    float ov = acc[ot + 12][r];
                    float c = sigf(fv) * c_r[ot][r] + sigf(iv) * tanhf_(gv);
                    c_r[ot][r] = c;
                    float h = sigf(ov) * tanhf_(c);
                    const int nodeL = q * 4 + r;
                    hlds[wv * 1152 + nodeL * 72 + ot * 16 + c16] = (bf16)h;
                    const int ng = node0 + nodeL;
                    if (ng < NN) {
                        float* po = out + (ng * 8 + t) * 64 + ot * 16 + c16;
                        *po = (l == 0) ? h : fmaxf(*po, h);
                        if (t == TT - 1) {
                            float* ph = out + NN * 8 * 64 + ng * 64 + ot * 16 + c16;
                            float* pc = ph + NN * 64;
                            if (l == 0) { *ph = h; *pc = c; }
                            else        { *ph = fmaxf(*ph, h); *pc = fmaxf(*pc, c); }
                        }
                    }
                }
            }
            __syncthreads();  // h written before next step's A-frag reads
        }
    }
}

extern "C" void kernel_launch(void* const* d_in, const int* in_sizes, int n_in,
                              void* d_out, int out_size, void* d_ws, size_t ws_size,
                              hipStream_t stream) {
    const float* X = (const float*)d_in[0];
    const int* As = (const int*)d_in[1];
    // d_in[2] key_out, d_in[3] key_states: unused
    const float* conv_w = (const float*)d_in[4];
    const float* conv_b = (const float*)d_in[5];
    const float* W_ih = (const float*)d_in[6];
    const float* W_hh = (const float*)d_in[7];
    const float* b_ih = (const float*)d_in[8];
    const float* b_hh = (const float*)d_in[9];
    float* out = (float*)d_out;

    char* ws = (char*)d_ws;
    bf16* feat = (bf16*)ws;                                   // L*T*N*64 bf16 = 30,720,000 B
    bf16* wts = (bf16*)(ws + 30720000);                       // 98,304 bf16 = 196,608 B
    float* bias = (float*)(ws + 30720000 + 196608);           // 768 f32 = 3,072 B

    hipLaunchKernelGGL(prep_kernel, dim3(387), dim3(256), 0, stream,
                       W_ih, W_hh, b_ih, b_hh, wts, bias);
    hipLaunchKernelGGL(conv_kernel, dim3(LL * TT * NCHUNK), dim3(256), 0, stream,
                       X, As, conv_w, conv_b, feat);
    hipLaunchKernelGGL(lstm_kernel, dim3(NCHUNK), dim3(256), 0, stream,
                       feat, wts, bias, out);
}

// Round 2
// 240.842 us; speedup vs baseline: 1.4064x; 1.4064x over previous
//
#include <hip/hip_runtime.h>
#include <hip/hip_bf16.h>

#define NN 10000
#define TT 8
#define CC 16
#define OO 64
#define KK 16
#define LL 3
#define NGRP 625     // 10000 / 16 exactly

typedef __bf16 bf16;
typedef __attribute__((ext_vector_type(8))) __bf16 bf16x8;
typedef __attribute__((ext_vector_type(4))) float f32x4;

__device__ __forceinline__ float sigf(float x) { return 1.0f / (1.0f + __expf(-x)); }
__device__ __forceinline__ float tanhf_(float x) { return 2.0f / (1.0f + __expf(-2.0f * x)) - 1.0f; }

// ---------------------------------------------------------------------------
// prep: repack LSTM weights into bf16 B-fragment order + combine biases.
// wts layout (bf16): [l][mat][kh][nt][n16][k32]
// ---------------------------------------------------------------------------
__global__ void prep_kernel(const float* __restrict__ W_ih, const float* __restrict__ W_hh,
                            const float* __restrict__ b_ih, const float* __restrict__ b_hh,
                            bf16* __restrict__ wts, float* __restrict__ bias) {
    int id = blockIdx.x * 256 + threadIdx.x;
    if (id < LL * 2 * 256 * 64) {
        int col = id & 63;
        int row = (id >> 6) & 255;
        int mat = (id >> 14) & 1;
        int l = id >> 15;
        const float* src = mat ? W_hh : W_ih;
        float w = src[(l * 256 + row) * 64 + col];
        int kh = col >> 5, nt = row >> 4, nn = row & 15, kk = col & 31;
        wts[((((l * 2 + mat) * 2 + kh) * 16 + nt) * 16 + nn) * 32 + kk] = (bf16)w;
    } else {
        int id2 = id - LL * 2 * 256 * 64;
        if (id2 < LL * 256) bias[id2] = b_ih[id2] + b_hh[id2];
    }
}

// ---------------------------------------------------------------------------
// conv: grid = L*T*NGRP blocks, 256 thr (4 waves), wave = 4 nodes.
// All idx/self/gather loads batched up front (independent latency chains),
// then 16 independent MFMAs + shfl-max + store.
// ---------------------------------------------------------------------------
__global__ __launch_bounds__(256) void conv_kernel(
    const float* __restrict__ X, const int* __restrict__ As,
    const float* __restrict__ conv_w, const float* __restrict__ conv_b,
    bf16* __restrict__ feat) {
    const int lane = threadIdx.x & 63;
    const int wv = threadIdx.x >> 6;
    const int c16 = lane & 15;  // A-row (neighbor) / B-col (output) index
    const int q = lane >> 4;

    const int grp = blockIdx.x % NGRP;
    const int lt = blockIdx.x / NGRP;
    const int l = lt >> 3, t = lt & 7;

    // B-fragments: B[k=c][n=o'] = conv_w[l][nt*16+o'][c]; quads 2,3 zero pad.
    bf16x8 bw[4];
#pragma unroll
    for (int nt = 0; nt < 4; ++nt) {
        bf16x8 b;
#pragma unroll
        for (int j = 0; j < 8; ++j) b[j] = (bf16)0.0f;
        if (q < 2) {
            const float* wp = conv_w + ((l * 64 + nt * 16 + c16) * 16 + q * 8);
            f32x4 w0 = *(const f32x4*)wp;
            f32x4 w1 = *(const f32x4*)(wp + 4);
#pragma unroll
            for (int j = 0; j < 4; ++j) { b[j] = (bf16)w0[j]; b[4 + j] = (bf16)w1[j]; }
        }
        bw[nt] = b;
    }
    const float bias_v = conv_b[l * 64 + q * 16 + c16];

    const int nbase = grp * 16 + wv * 4;
    const int ltbase = (l * 8 + t) * NN;

    int aidx[4];
#pragma unroll
    for (int j = 0; j < 4; ++j)
        aidx[j] = As[((long)ltbase + nbase + j) * 16 + c16];

    f32x4 sv[4][2], gv[4][2];
    if (q < 2) {
#pragma unroll
        for (int j = 0; j < 4; ++j) {
            const float* sp = X + ((nbase + j) * 8 + t) * 16 + q * 8;
            sv[j][0] = *(const f32x4*)sp;
            sv[j][1] = *(const f32x4*)(sp + 4);
        }
#pragma unroll
        for (int j = 0; j < 4; ++j) {
            const float* gp = X + (aidx[j] * 8 + t) * 16 + q * 8;
            gv[j][0] = *(const f32x4*)gp;
            gv[j][1] = *(const f32x4*)(gp + 4);
        }
    }

#pragma unroll
    for (int j = 0; j < 4; ++j) {
        bf16x8 af;
#pragma unroll
        for (int k = 0; k < 8; ++k) af[k] = (bf16)0.0f;
        if (q < 2) {
#pragma unroll
            for (int k = 0; k < 4; ++k) {
                af[k]     = (bf16)(gv[j][0][k] - sv[j][0][k]);
                af[4 + k] = (bf16)(gv[j][1][k] - sv[j][1][k]);
            }
        }
        f32x4 a0 = {0.f, 0.f, 0.f, 0.f}, a1 = a0, a2 = a0, a3 = a0;
        a0 = __builtin_amdgcn_mfma_f32_16x16x32_bf16(af, bw[0], a0, 0, 0, 0);
        a1 = __builtin_amdgcn_mfma_f32_16x16x32_bf16(af, bw[1], a1, 0, 0, 0);
        a2 = __builtin_amdgcn_mfma_f32_16x16x32_bf16(af, bw[2], a2, 0, 0, 0);
        a3 = __builtin_amdgcn_mfma_f32_16x16x32_bf16(af, bw[3], a3, 0, 0, 0);

        float m0 = fmaxf(fmaxf(a0[0], a0[1]), fmaxf(a0[2], a0[3]));
        float m1 = fmaxf(fmaxf(a1[0], a1[1]), fmaxf(a1[2], a1[3]));
        float m2 = fmaxf(fmaxf(a2[0], a2[1]), fmaxf(a2[2], a2[3]));
        float m3 = fmaxf(fmaxf(a3[0], a3[1]), fmaxf(a3[2], a3[3]));
        m0 = fmaxf(m0, __shfl_xor(m0, 16)); m0 = fmaxf(m0, __shfl_xor(m0, 32));
        m1 = fmaxf(m1, __shfl_xor(m1, 16)); m1 = fmaxf(m1, __shfl_xor(m1, 32));
        m2 = fmaxf(m2, __shfl_xor(m2, 16)); m2 = fmaxf(m2, __shfl_xor(m2, 32));
        m3 = fmaxf(m3, __shfl_xor(m3, 16)); m3 = fmaxf(m3, __shfl_xor(m3, 32));
        float v = (q & 2) ? ((q & 1) ? m3 : m2) : ((q & 1) ? m1 : m0);
        feat[((long)ltbase + nbase + j) * 64 + q * 16 + c16] = (bf16)(v + bias_v);
    }
}

// ---------------------------------------------------------------------------
// lstm: 625 blocks x 4 waves; block owns 16 nodes; wave w owns gate tiles
// {w, 4+w, 8+w, 12+w} = all i/f/g/o for hidden cols [16w,16w+16).
// Weights in REGISTERS (16 B-frags/wave, reloaded per level). h exchanged
// via tiny double-buffered LDS, one sync/step. ys/h/c maxes over L kept in
// registers (T unrolled); out written once at the end.
// ---------------------------------------------------------------------------
__global__ __launch_bounds__(256, 3) void lstm_kernel(
    const bf16* __restrict__ feat, const bf16* __restrict__ wts,
    const float* __restrict__ bias, float* __restrict__ out) {
    __shared__ __align__(16) bf16 hlds[2][16][72];  // 4.6 KB

    const int tid = threadIdx.x;
    const int lane = tid & 63;
    const int wv = tid >> 6;
    const int c16 = lane & 15;
    const int q = lane >> 4;
    const int node0 = blockIdx.x * 16;   // 625*16 == 10000 exactly, no masking
    const int nA = node0 + c16;

    float ymax[TT][4];
#pragma unroll
    for (int t = 0; t < TT; ++t)
#pragma unroll
        for (int r = 0; r < 4; ++r) ymax[t][r] = -3.0e38f;
    float hfin[4], cfin[4];
#pragma unroll
    for (int r = 0; r < 4; ++r) { hfin[r] = -3.0e38f; cfin[r] = -3.0e38f; }

    for (int l = 0; l < LL; ++l) {
        // --- per-level weight fragments into registers ---
        const bf16* wb = wts + l * 32768;
        const int fo = c16 * 32 + q * 8;
        bf16x8 Bx0[4], Bx1[4], Bh0[4], Bh1[4];
        float brg[4];
#pragma unroll
        for (int g = 0; g < 4; ++g) {
            const int nt = 4 * g + wv;
            Bx0[g] = *(const bf16x8*)(wb + (0 * 16 + nt) * 512 + fo);
            Bx1[g] = *(const bf16x8*)(wb + (1 * 16 + nt) * 512 + fo);
            Bh0[g] = *(const bf16x8*)(wb + (2 * 16 + nt) * 512 + fo);
            Bh1[g] = *(const bf16x8*)(wb + (3 * 16 + nt) * 512 + fo);
            brg[g] = bias[l * 256 + nt * 16 + c16];
        }

        float c_r[4];
#pragma unroll
        for (int r = 0; r < 4; ++r) c_r[r] = 0.0f;

        // prefetch x for t=0
        const bf16* f0 = feat + ((long)(l * 8 + 0) * NN + nA) * 64;
        bf16x8 px0 = *(const bf16x8*)(f0 + q * 8);
        bf16x8 px1 = *(const bf16x8*)(f0 + 32 + q * 8);

#pragma unroll
        for (int t = 0; t < TT; ++t) {
            bf16x8 ax0 = px0, ax1 = px1;
            if (t < TT - 1) {
                const bf16* fn = feat + ((long)(l * 8 + t + 1) * NN + nA) * 64;
                px0 = *(const bf16x8*)(fn + q * 8);
                px1 = *(const bf16x8*)(fn + 32 + q * 8);
            }
            __syncthreads();  // h(t-1) visible; also protects level-boundary reuse

            bf16x8 ah0, ah1;
            if (t > 0) {
                const bf16* hb = &hlds[(t + 1) & 1][c16][q * 8];
                ah0 = *(const bf16x8*)hb;
                ah1 = *(const bf16x8*)(hb + 32);
            }

            f32x4 acc[4];
#pragma unroll
            for (int g = 0; g < 4; ++g) {
                float b = brg[g];
                acc[g] = (f32x4){b, b, b, b};
                acc[g] = __builtin_amdgcn_mfma_f32_16x16x32_bf16(ax0, Bx0[g], acc[g], 0, 0, 0);
                acc[g] = __builtin_amdgcn_mfma_f32_16x16x32_bf16(ax1, Bx1[g], acc[g], 0, 0, 0);
                if (t > 0) {
                    acc[g] = __builtin_amdgcn_mfma_f32_16x16x32_bf16(ah0, Bh0[g], acc[g], 0, 0, 0);
                    acc[g] = __builtin_amdgcn_mfma_f32_16x16x32_bf16(ah1, Bh1[g], acc[g], 0, 0, 0);
                }
            }

            // cell: lane holds node q*4+r, hidden col wv*16+c16
#pragma unroll
            for (int r = 0; r < 4; ++r) {
                float iv = acc[0][r], fv = acc[1][r], gv = acc[2][r], ov = acc[3][r];
                float c = sigf(fv) * c_r[r] + sigf(iv) * tanhf_(gv);
                c_r[r] = c;
                float h = sigf(ov) * tanhf_(c);
                hlds[t & 1][q * 4 + r][wv * 16 + c16] = (bf16)h;
                ymax[t][r] = fmaxf(ymax[t][r], h);
                if (t == TT - 1) {
                    hfin[r] = fmaxf(hfin[r], h);
                    cfin[r] = fmaxf(cfin[r], c);
                }
            }
        }
    }

    // --- final stores (each element written exactly once) ---
    const int col = wv * 16 + c16;
#pragma unroll
    for (int t = 0; t < TT; ++t)
#pragma unroll
        for (int r = 0; r < 4; ++r)
            out[((long)(node0 + q * 4 + r) * 8 + t) * 64 + col] = ymax[t][r];
    float* sh = out + (long)NN * 8 * 64;
    float* sc = sh + (long)NN * 64;
#pragma unroll
    for (int r = 0; r < 4; ++r) {
        sh[(long)(node0 + q * 4 + r) * 64 + col] = hfin[r];
        sc[(long)(node0 + q * 4 + r) * 64 + col] = cfin[r];
    }
}

extern "C" void kernel_launch(void* const* d_in, const int* in_sizes, int n_in,
                              void* d_out, int out_size, void* d_ws, size_t ws_size,
                              hipStream_t stream) {
    const float* X = (const float*)d_in[0];
    const int* As = (const int*)d_in[1];
    const float* conv_w = (const float*)d_in[4];
    const float* conv_b = (const float*)d_in[5];
    const float* W_ih = (const float*)d_in[6];
    const float* W_hh = (const float*)d_in[7];
    const float* b_ih = (const float*)d_in[8];
    const float* b_hh = (const float*)d_in[9];
    float* out = (float*)d_out;

    char* ws = (char*)d_ws;
    bf16* feat = (bf16*)ws;                                   // L*T*N*64 bf16 = 30,720,000 B
    bf16* wts = (bf16*)(ws + 30720000);                       // 98,304 bf16
    float* bias = (float*)(ws + 30720000 + 196608);           // 768 f32

    hipLaunchKernelGGL(prep_kernel, dim3(387), dim3(256), 0, stream,
                       W_ih, W_hh, b_ih, b_hh, wts, bias);
    hipLaunchKernelGGL(conv_kernel, dim3(LL * TT * NGRP), dim3(256), 0, stream,
                       X, As, conv_w, conv_b, feat);
    hipLaunchKernelGGL(lstm_kernel, dim3(NGRP), dim3(256), 0, stream,
                       feat, wts, bias, out);
}

// Round 3
// 213.247 us; speedup vs baseline: 1.5883x; 1.1294x over previous
//
#include <hip/hip_runtime.h>
#include <hip/hip_bf16.h>

#define NN 10000
#define TT 8
#define CC 16
#define OO 64
#define KK 16
#define LL 3
#define NGRP 625     // 10000 / 16 exactly

typedef __bf16 bf16;
typedef __attribute__((ext_vector_type(8))) __bf16 bf16x8;
typedef __attribute__((ext_vector_type(4))) float f32x4;
typedef __attribute__((ext_vector_type(16))) float f32x16;

__device__ __forceinline__ float sigf(float x) { return 1.0f / (1.0f + __expf(-x)); }
__device__ __forceinline__ float tanhf_(float x) { return 2.0f / (1.0f + __expf(-2.0f * x)) - 1.0f; }

// ---------------------------------------------------------------------------
// prep: repack LSTM weights into bf16 B-fragment order + combine biases.
// wts layout (bf16): [l][mat][kh][nt][n16][k32]
// ---------------------------------------------------------------------------
__global__ void prep_kernel(const float* __restrict__ W_ih, const float* __restrict__ W_hh,
                            const float* __restrict__ b_ih, const float* __restrict__ b_hh,
                            bf16* __restrict__ wts, float* __restrict__ bias) {
    int id = blockIdx.x * 256 + threadIdx.x;
    if (id < LL * 2 * 256 * 64) {
        int col = id & 63;
        int row = (id >> 6) & 255;
        int mat = (id >> 14) & 1;
        int l = id >> 15;
        const float* src = mat ? W_hh : W_ih;
        float w = src[(l * 256 + row) * 64 + col];
        int kh = col >> 5, nt = row >> 4, nn = row & 15, kk = col & 31;
        wts[((((l * 2 + mat) * 2 + kh) * 16 + nt) * 16 + nn) * 32 + kk] = (bf16)w;
    } else {
        int id2 = id - LL * 2 * 256 * 64;
        if (id2 < LL * 256) bias[id2] = b_ih[id2] + b_hh[id2];
    }
}

// ---------------------------------------------------------------------------
// conv via mfma_f32_32x32x16_bf16: M=32 = 2 nodes x 16 neighbors, K=16=C
// exactly (no padding), N=32 = half the output channels. 2 MFMAs per node
// pair, all 64 lanes carry useful A data.
// A layout: m = lane&31, k = (lane>>5)*8 + j.  B: n = lane&31, same k.
// C/D: col = lane&31, row = (reg&3) + 8*(reg>>2) + 4*(lane>>5)
//   -> node0 (rows 0..15) = regs 0..7, node1 (rows 16..31) = regs 8..15,
//      lane halves merged with one shfl_xor(32).
// grid = L*T*NGRP blocks, 4 waves/block, wave = 2 pairs = 4 nodes.
// ---------------------------------------------------------------------------
__global__ __launch_bounds__(256) void conv_kernel(
    const float* __restrict__ X, const int* __restrict__ As,
    const float* __restrict__ conv_w, const float* __restrict__ conv_b,
    bf16* __restrict__ feat) {
    const int lane = threadIdx.x & 63;
    const int wv = threadIdx.x >> 6;
    const int m = lane & 31;       // A row: (node within pair)<<4 | neighbor
    const int hh = lane >> 5;      // k-half
    const int ch0 = hh * 8;

    const int grp = blockIdx.x % NGRP;
    const int lt = blockIdx.x / NGRP;
    const int l = lt >> 3, t = lt & 7;
    const long ltN = (long)lt * NN;

    // B-fragments: B[k=c][n=o] = conv_w[l][o][c]
    bf16x8 B0, B1;
    {
        const float* w0 = conv_w + ((l * 64 + m) * 16 + ch0);
        f32x4 a = *(const f32x4*)w0, b = *(const f32x4*)(w0 + 4);
        const float* w1 = conv_w + ((l * 64 + 32 + m) * 16 + ch0);
        f32x4 c = *(const f32x4*)w1, d = *(const f32x4*)(w1 + 4);
#pragma unroll
        for (int j = 0; j < 4; ++j) {
            B0[j] = (bf16)a[j]; B0[4 + j] = (bf16)b[j];
            B1[j] = (bf16)c[j]; B1[4 + j] = (bf16)d[j];
        }
    }
    const float b0 = conv_b[l * 64 + m];
    const float b1 = conv_b[l * 64 + 32 + m];

    const int nbase = grp * 16 + wv * 4;
    const int nsub = m >> 4;   // node within pair
    const int kn = m & 15;     // neighbor index

    // batched loads for both pairs (independent latency chains)
    int aidx[2];
#pragma unroll
    for (int p = 0; p < 2; ++p) {
        const int node = nbase + 2 * p + nsub;
        aidx[p] = As[(ltN + node) * 16 + kn];
    }
    f32x4 sv[2][2], gv[2][2];
#pragma unroll
    for (int p = 0; p < 2; ++p) {
        const int node = nbase + 2 * p + nsub;
        const float* sp = X + ((node * 8 + t) * 16 + ch0);
        sv[p][0] = *(const f32x4*)sp;
        sv[p][1] = *(const f32x4*)(sp + 4);
    }
#pragma unroll
    for (int p = 0; p < 2; ++p) {
        const float* gp = X + (((long)aidx[p] * 8 + t) * 16 + ch0);
        gv[p][0] = *(const f32x4*)gp;
        gv[p][1] = *(const f32x4*)(gp + 4);
    }

#pragma unroll
    for (int p = 0; p < 2; ++p) {
        bf16x8 af;
#pragma unroll
        for (int j = 0; j < 4; ++j) {
            af[j]     = (bf16)(gv[p][0][j] - sv[p][0][j]);
            af[4 + j] = (bf16)(gv[p][1][j] - sv[p][1][j]);
        }
        f32x16 D0, D1;
#pragma unroll
        for (int j = 0; j < 16; ++j) { D0[j] = 0.0f; D1[j] = 0.0f; }
        D0 = __builtin_amdgcn_mfma_f32_32x32x16_bf16(af, B0, D0, 0, 0, 0);
        D1 = __builtin_amdgcn_mfma_f32_32x32x16_bf16(af, B1, D1, 0, 0, 0);

        // max over neighbors: node0 = regs 0..7, node1 = regs 8..15
        float v00 = D0[0], v01 = D1[0], v10 = D0[8], v11 = D1[8];
#pragma unroll
        for (int j = 1; j < 8; ++j) {
            v00 = fmaxf(v00, D0[j]);     v01 = fmaxf(v01, D1[j]);
            v10 = fmaxf(v10, D0[8 + j]); v11 = fmaxf(v11, D1[8 + j]);
        }
        v00 = fmaxf(v00, __shfl_xor(v00, 32));
        v01 = fmaxf(v01, __shfl_xor(v01, 32));
        v10 = fmaxf(v10, __shfl_xor(v10, 32));
        v11 = fmaxf(v11, __shfl_xor(v11, 32));

        const float sA = hh ? v10 : v00;   // cols [0,32)
        const float sB = hh ? v11 : v01;   // cols [32,64)
        const int nst = nbase + 2 * p + hh;
        bf16* fo = feat + (ltN + nst) * 64;
        fo[m]      = (bf16)(sA + b0);
        fo[32 + m] = (bf16)(sB + b1);
    }
}

// ---------------------------------------------------------------------------
// lstm: 625 blocks x 4 waves; block owns 16 nodes; wave w owns gate tiles
// {w, 4+w, 8+w, 12+w} = all i/f/g/o for hidden cols [16w,16w+16).
// Weights in REGISTERS (16 B-frags/wave, reloaded per level). h exchanged
// via tiny double-buffered LDS, one sync/step. ys/h/c maxes over L kept in
// registers (T unrolled); out written once at the end.
// ---------------------------------------------------------------------------
__global__ __launch_bounds__(256, 3) void lstm_kernel(
    const bf16* __restrict__ feat, const bf16* __restrict__ wts,
    const float* __restrict__ bias, float* __restrict__ out) {
    __shared__ __align__(16) bf16 hlds[2][16][72];  // 4.6 KB

    const int tid = threadIdx.x;
    const int lane = tid & 63;
    const int wv = tid >> 6;
    const int c16 = lane & 15;
    const int q = lane >> 4;
    const int node0 = blockIdx.x * 16;   // 625*16 == 10000 exactly, no masking
    const int nA = node0 + c16;

    float ymax[TT][4];
#pragma unroll
    for (int t = 0; t < TT; ++t)
#pragma unroll
        for (int r = 0; r < 4; ++r) ymax[t][r] = -3.0e38f;
    float hfin[4], cfin[4];
#pragma unroll
    for (int r = 0; r < 4; ++r) { hfin[r] = -3.0e38f; cfin[r] = -3.0e38f; }

    for (int l = 0; l < LL; ++l) {
        // --- per-level weight fragments into registers ---
        const bf16* wb = wts + l * 32768;
        const int fo = c16 * 32 + q * 8;
        bf16x8 Bx0[4], Bx1[4], Bh0[4], Bh1[4];
        float brg[4];
#pragma unroll
        for (int g = 0; g < 4; ++g) {
            const int nt = 4 * g + wv;
            Bx0[g] = *(const bf16x8*)(wb + (0 * 16 + nt) * 512 + fo);
            Bx1[g] = *(const bf16x8*)(wb + (1 * 16 + nt) * 512 + fo);
            Bh0[g] = *(const bf16x8*)(wb + (2 * 16 + nt) * 512 + fo);
            Bh1[g] = *(const bf16x8*)(wb + (3 * 16 + nt) * 512 + fo);
            brg[g] = bias[l * 256 + nt * 16 + c16];
        }

        float c_r[4];
#pragma unroll
        for (int r = 0; r < 4; ++r) c_r[r] = 0.0f;

        // prefetch x for t=0
        const bf16* f0 = feat + ((long)(l * 8 + 0) * NN + nA) * 64;
        bf16x8 px0 = *(const bf16x8*)(f0 + q * 8);
        bf16x8 px1 = *(const bf16x8*)(f0 + 32 + q * 8);

#pragma unroll
        for (int t = 0; t < TT; ++t) {
            bf16x8 ax0 = px0, ax1 = px1;
            if (t < TT - 1) {
                const bf16* fn = feat + ((long)(l * 8 + t + 1) * NN + nA) * 64;
                px0 = *(const bf16x8*)(fn + q * 8);
                px1 = *(const bf16x8*)(fn + 32 + q * 8);
            }
            __syncthreads();  // h(t-1) visible; also protects level-boundary reuse

            bf16x8 ah0, ah1;
            if (t > 0) {
                const bf16* hb = &hlds[(t + 1) & 1][c16][q * 8];
                ah0 = *(const bf16x8*)hb;
                ah1 = *(const bf16x8*)(hb + 32);
            }

            f32x4 acc[4];
#pragma unroll
            for (int g = 0; g < 4; ++g) {
                float b = brg[g];
                acc[g] = (f32x4){b, b, b, b};
                acc[g] = __builtin_amdgcn_mfma_f32_16x16x32_bf16(ax0, Bx0[g], acc[g], 0, 0, 0);
                acc[g] = __builtin_amdgcn_mfma_f32_16x16x32_bf16(ax1, Bx1[g], acc[g], 0, 0, 0);
                if (t > 0) {
                    acc[g] = __builtin_amdgcn_mfma_f32_16x16x32_bf16(ah0, Bh0[g], acc[g], 0, 0, 0);
                    acc[g] = __builtin_amdgcn_mfma_f32_16x16x32_bf16(ah1, Bh1[g], acc[g], 0, 0, 0);
                }
            }

            // cell: lane holds node q*4+r, hidden col wv*16+c16
#pragma unroll
            for (int r = 0; r < 4; ++r) {
                float iv = acc[0][r], fv = acc[1][r], gv = acc[2][r], ov = acc[3][r];
                float c = sigf(fv) * c_r[r] + sigf(iv) * tanhf_(gv);
                c_r[r] = c;
                float h = sigf(ov) * tanhf_(c);
                hlds[t & 1][q * 4 + r][wv * 16 + c16] = (bf16)h;
                ymax[t][r] = fmaxf(ymax[t][r], h);
                if (t == TT - 1) {
                    hfin[r] = fmaxf(hfin[r], h);
                    cfin[r] = fmaxf(cfin[r], c);
                }
            }
        }
    }

    // --- final stores (each element written exactly once) ---
    const int col = wv * 16 + c16;
#pragma unroll
    for (int t = 0; t < TT; ++t)
#pragma unroll
        for (int r = 0; r < 4; ++r)
            out[((long)(node0 + q * 4 + r) * 8 + t) * 64 + col] = ymax[t][r];
    float* sh = out + (long)NN * 8 * 64;
    float* sc = sh + (long)NN * 64;
#pragma unroll
    for (int r = 0; r < 4; ++r) {
        sh[(long)(node0 + q * 4 + r) * 64 + col] = hfin[r];
        sc[(long)(node0 + q * 4 + r) * 64 + col] = cfin[r];
    }
}

extern "C" void kernel_launch(void* const* d_in, const int* in_sizes, int n_in,
                              void* d_out, int out_size, void* d_ws, size_t ws_size,
                              hipStream_t stream) {
    const float* X = (const float*)d_in[0];
    const int* As = (const int*)d_in[1];
    const float* conv_w = (const float*)d_in[4];
    const float* conv_b = (const float*)d_in[5];
    const float* W_ih = (const float*)d_in[6];
    const float* W_hh = (const float*)d_in[7];
    const float* b_ih = (const float*)d_in[8];
    const float* b_hh = (const float*)d_in[9];
    float* out = (float*)d_out;

    char* ws = (char*)d_ws;
    bf16* feat = (bf16*)ws;                                   // L*T*N*64 bf16 = 30,720,000 B
    bf16* wts = (bf16*)(ws + 30720000);                       // 98,304 bf16
    float* bias = (float*)(ws + 30720000 + 196608);           // 768 f32

    hipLaunchKernelGGL(prep_kernel, dim3(387), dim3(256), 0, stream,
                       W_ih, W_hh, b_ih, b_hh, wts, bias);
    hipLaunchKernelGGL(conv_kernel, dim3(LL * TT * NGRP), dim3(256), 0, stream,
                       X, As, conv_w, conv_b, feat);
    hipLaunchKernelGGL(lstm_kernel, dim3(NGRP), dim3(256), 0, stream,
                       feat, wts, bias, out);
}

// Round 4
// 211.993 us; speedup vs baseline: 1.5977x; 1.0059x over previous
//
#include <hip/hip_runtime.h>
#include <hip/hip_bf16.h>

#define NN 10000
#define TT 8
#define LL 3
#define NGRP 625     // 10000 / 16 exactly

typedef __bf16 bf16;
typedef __attribute__((ext_vector_type(8))) __bf16 bf16x8;
typedef __attribute__((ext_vector_type(4))) float f32x4;
typedef __attribute__((ext_vector_type(16))) float f32x16;

// v_rcp_f32 (1 instr) instead of IEEE divide (~10 instrs) — bf16-grade accuracy.
__device__ __forceinline__ float sigf(float x) {
    return __builtin_amdgcn_rcpf(1.0f + __expf(-x));
}
__device__ __forceinline__ float tanhf_(float x) {
    return fmaf(2.0f, __builtin_amdgcn_rcpf(1.0f + __expf(-2.0f * x)), -1.0f);
}

// ---------------------------------------------------------------------------
// prep: repack LSTM weights into bf16 B-fragment order + combine biases.
// wts layout (bf16): [l][mat][kh][nt][n16][k32]
// ---------------------------------------------------------------------------
__global__ void prep_kernel(const float* __restrict__ W_ih, const float* __restrict__ W_hh,
                            const float* __restrict__ b_ih, const float* __restrict__ b_hh,
                            bf16* __restrict__ wts, float* __restrict__ bias) {
    int id = blockIdx.x * 256 + threadIdx.x;
    if (id < LL * 2 * 256 * 64) {
        int col = id & 63;
        int row = (id >> 6) & 255;
        int mat = (id >> 14) & 1;
        int l = id >> 15;
        const float* src = mat ? W_hh : W_ih;
        float w = src[(l * 256 + row) * 64 + col];
        int kh = col >> 5, nt = row >> 4, nn = row & 15, kk = col & 31;
        wts[((((l * 2 + mat) * 2 + kh) * 16 + nt) * 16 + nn) * 32 + kk] = (bf16)w;
    } else {
        int id2 = id - LL * 2 * 256 * 64;
        if (id2 < LL * 256) bias[id2] = b_ih[id2] + b_hh[id2];
    }
}

// ---------------------------------------------------------------------------
// fused conv+lstm: 625 blocks x 1024 threads (16 waves); block owns 16 nodes,
// loops levels in-block (max-over-L stays in registers).
// Per level: conv stage (each wave: 1 node-pair x 4 t, 32x32x16 MFMA, K=C=16
// exact) writes feat tiles into LDS; then 8 LSTM steps where wave wv computes
// ONE 16x16 gate tile (4 MFMAs), i/f/g/o are exchanged through a padded LDS
// gate buffer, and 1024 threads each run ONE cell (1 per (node,col)).
// ---------------------------------------------------------------------------
__global__ __launch_bounds__(1024, 4) void fused_kernel(
    const float* __restrict__ X, const int* __restrict__ As,
    const float* __restrict__ conv_w, const float* __restrict__ conv_b,
    const bf16* __restrict__ wts, const float* __restrict__ bias,
    float* __restrict__ out) {
    __shared__ __align__(16) bf16 featL[TT][16][72];   // 18.4 KB (72-pad rows)
    __shared__ __align__(16) bf16 hlds[2][16][72];     // 4.6 KB
    __shared__ __align__(16) float gates[4][64][20];   // 20.5 KB (20-pad: bank spread)

    const int tid = threadIdx.x;
    const int lane = tid & 63;
    const int wv = tid >> 6;        // 0..15
    const int c16 = lane & 15;
    const int q = lane >> 4;
    const int m = lane & 31;
    const int hh = lane >> 5;
    const int node0 = blockIdx.x * 16;

    // cell-thread mapping: 1024 threads -> (node, col), LDS-bank friendly
    const int cnode = (tid >> 2) & 15;
    const int ccol = ((tid >> 6) << 2) | (tid & 3);

    // conv assignment: wave handles pair cp (nodes 2cp,2cp+1), t in [t0c, t0c+4)
    const int cp = wv >> 1;
    const int t0c = (wv & 1) * 4;
    const int nsub = m >> 4;        // node within pair (for loads)
    const int kn = m & 15;          // neighbor index
    const int ch0 = hh * 8;         // channel half

    float ymax[TT];
#pragma unroll
    for (int t = 0; t < TT; ++t) ymax[t] = -3.0e38f;
    float hfin = -3.0e38f, cfin = -3.0e38f;

    for (int l = 0; l < LL; ++l) {
        __syncthreads();  // featL/hlds/gates from previous level fully consumed

        // ================= conv stage =================
        bf16x8 B0, B1;
        {
            const float* w0 = conv_w + ((l * 64 + m) * 16 + ch0);
            f32x4 a = *(const f32x4*)w0, b = *(const f32x4*)(w0 + 4);
            const float* w1 = conv_w + ((l * 64 + 32 + m) * 16 + ch0);
            f32x4 c = *(const f32x4*)w1, d = *(const f32x4*)(w1 + 4);
#pragma unroll
            for (int j = 0; j < 4; ++j) {
                B0[j] = (bf16)a[j]; B0[4 + j] = (bf16)b[j];
                B1[j] = (bf16)c[j]; B1[4 + j] = (bf16)d[j];
            }
        }
        const float b0 = conv_b[l * 64 + m];
        const float b1 = conv_b[l * 64 + 32 + m];

        const int nl = 2 * cp + nsub;       // local node for this lane's loads
        const int gn = node0 + nl;

        int aidx[4];
        f32x4 sv[4][2], gv[4][2];
#pragma unroll
        for (int j = 0; j < 4; ++j) {
            const int t = t0c + j;
            aidx[j] = As[((long)(l * 8 + t) * NN + gn) * 16 + kn];
        }
#pragma unroll
        for (int j = 0; j < 4; ++j) {
            const int t = t0c + j;
            const float* sp = X + ((gn * 8 + t) * 16 + ch0);
            sv[j][0] = *(const f32x4*)sp;
            sv[j][1] = *(const f32x4*)(sp + 4);
        }
#pragma unroll
        for (int j = 0; j < 4; ++j) {
            const int t = t0c + j;
            const float* gp = X + ((aidx[j] * 8 + t) * 16 + ch0);
            gv[j][0] = *(const f32x4*)gp;
            gv[j][1] = *(const f32x4*)(gp + 4);
        }

#pragma unroll
        for (int j = 0; j < 4; ++j) {
            const int t = t0c + j;
            bf16x8 af;
#pragma unroll
            for (int k = 0; k < 4; ++k) {
                af[k]     = (bf16)(gv[j][0][k] - sv[j][0][k]);
                af[4 + k] = (bf16)(gv[j][1][k] - sv[j][1][k]);
            }
            f32x16 D0, D1;
#pragma unroll
            for (int k = 0; k < 16; ++k) { D0[k] = 0.0f; D1[k] = 0.0f; }
            D0 = __builtin_amdgcn_mfma_f32_32x32x16_bf16(af, B0, D0, 0, 0, 0);
            D1 = __builtin_amdgcn_mfma_f32_32x32x16_bf16(af, B1, D1, 0, 0, 0);

            // max over neighbors: node-sub0 = regs 0..7, node-sub1 = regs 8..15
            float v00 = D0[0], v01 = D1[0], v10 = D0[8], v11 = D1[8];
#pragma unroll
            for (int k = 1; k < 8; ++k) {
                v00 = fmaxf(v00, D0[k]);     v01 = fmaxf(v01, D1[k]);
                v10 = fmaxf(v10, D0[8 + k]); v11 = fmaxf(v11, D1[8 + k]);
            }
            v00 = fmaxf(v00, __shfl_xor(v00, 32));
            v01 = fmaxf(v01, __shfl_xor(v01, 32));
            v10 = fmaxf(v10, __shfl_xor(v10, 32));
            v11 = fmaxf(v11, __shfl_xor(v11, 32));

            const float sA = hh ? v10 : v00;   // cols [0,32)
            const float sB = hh ? v11 : v01;   // cols [32,64)
            const int nst = 2 * cp + hh;
            featL[t][nst][m]      = (bf16)(sA + b0);
            featL[t][nst][32 + m] = (bf16)(sB + b1);
        }

        // ================= weights (registers) =================
        const bf16* wb = wts + l * 32768;
        const int fo = c16 * 32 + q * 8;
        bf16x8 Bx0 = *(const bf16x8*)(wb + (0 * 16 + wv) * 512 + fo);
        bf16x8 Bx1 = *(const bf16x8*)(wb + (1 * 16 + wv) * 512 + fo);
        bf16x8 Bh0 = *(const bf16x8*)(wb + (2 * 16 + wv) * 512 + fo);
        bf16x8 Bh1 = *(const bf16x8*)(wb + (3 * 16 + wv) * 512 + fo);
        const float brg = bias[l * 256 + wv * 16 + c16];
        float c_r = 0.0f;

        __syncthreads();  // featL fully written; gates free

        // ================= 8 LSTM steps =================
#pragma unroll
        for (int t = 0; t < TT; ++t) {
            bf16x8 ax0 = *(const bf16x8*)&featL[t][c16][q * 8];
            bf16x8 ax1 = *(const bf16x8*)&featL[t][c16][32 + q * 8];
            f32x4 acc = (f32x4){brg, brg, brg, brg};
            acc = __builtin_amdgcn_mfma_f32_16x16x32_bf16(ax0, Bx0, acc, 0, 0, 0);
            acc = __builtin_amdgcn_mfma_f32_16x16x32_bf16(ax1, Bx1, acc, 0, 0, 0);
            if (t > 0) {
                bf16x8 ah0 = *(const bf16x8*)&hlds[(t + 1) & 1][c16][q * 8];
                bf16x8 ah1 = *(const bf16x8*)&hlds[(t + 1) & 1][c16][32 + q * 8];
                acc = __builtin_amdgcn_mfma_f32_16x16x32_bf16(ah0, Bh0, acc, 0, 0, 0);
                acc = __builtin_amdgcn_mfma_f32_16x16x32_bf16(ah1, Bh1, acc, 0, 0, 0);
            }
            // publish gate tile: gt = wv>>2, col = (wv&3)*16+c16, nodes q*4..q*4+3
            *(f32x4*)&gates[wv >> 2][(wv & 3) * 16 + c16][q * 4] = acc;
            __syncthreads();

            // cell: one (node, col) per thread
            float iv = gates[0][ccol][cnode];
            float fv = gates[1][ccol][cnode];
            float gg = gates[2][ccol][cnode];
            float ov = gates[3][ccol][cnode];
            float c = sigf(fv) * c_r + sigf(iv) * tanhf_(gg);
            c_r = c;
            float h = sigf(ov) * tanhf_(c);
            hlds[t & 1][cnode][ccol] = (bf16)h;
            ymax[t] = fmaxf(ymax[t], h);
            if (t == TT - 1) { hfin = fmaxf(hfin, h); cfin = fmaxf(cfin, c); }
            __syncthreads();  // h visible for t+1; gates reusable
        }
    }

    // ================= final stores (written exactly once) =================
    const long gn2 = node0 + cnode;
#pragma unroll
    for (int t = 0; t < TT; ++t)
        out[(gn2 * 8 + t) * 64 + ccol] = ymax[t];
    float* sh = out + (long)NN * 8 * 64;
    float* sc = sh + (long)NN * 64;
    sh[gn2 * 64 + ccol] = hfin;
    sc[gn2 * 64 + ccol] = cfin;
}

extern "C" void kernel_launch(void* const* d_in, const int* in_sizes, int n_in,
                              void* d_out, int out_size, void* d_ws, size_t ws_size,
                              hipStream_t stream) {
    const float* X = (const float*)d_in[0];
    const int* As = (const int*)d_in[1];
    const float* conv_w = (const float*)d_in[4];
    const float* conv_b = (const float*)d_in[5];
    const float* W_ih = (const float*)d_in[6];
    const float* W_hh = (const float*)d_in[7];
    const float* b_ih = (const float*)d_in[8];
    const float* b_hh = (const float*)d_in[9];
    float* out = (float*)d_out;

    char* ws = (char*)d_ws;
    bf16* wts = (bf16*)ws;                      // 98,304 bf16 = 196,608 B
    float* bias = (float*)(ws + 196608);        // 768 f32

    hipLaunchKernelGGL(prep_kernel, dim3(387), dim3(256), 0, stream,
                       W_ih, W_hh, b_ih, b_hh, wts, bias);
    hipLaunchKernelGGL(fused_kernel, dim3(NGRP), dim3(1024), 0, stream,
                       X, As, conv_w, conv_b, wts, bias, out);
}